// Round 9
// baseline (1556.972 us; speedup 1.0000x reference)
//
#include <hip/hip_runtime.h>
#include <math.h>

#define B_   32
#define L_   1024
#define C_   32
#define D_   512
#define SEG_ 16
#define SX_  64
#define N_   1024   // B*C

typedef _Float16 f16x8 __attribute__((ext_vector_type(8)));
typedef _Float16 f16x4 __attribute__((ext_vector_type(4)));
typedef float    f32x4 __attribute__((ext_vector_type(4)));

__device__ __forceinline__ void stage16(const void* g, void* l) {
    __builtin_amdgcn_global_load_lds((const __attribute__((address_space(1))) void*)g,
                                     (__attribute__((address_space(3))) void*)l, 16, 0, 0);
}
// sc0|sc1: device-coherent (coherence-point) load -> LDS, cross-XCD safe
__device__ __forceinline__ void stage16c(const void* g, void* l) {
    __builtin_amdgcn_global_load_lds((const __attribute__((address_space(1))) void*)g,
                                     (__attribute__((address_space(3))) void*)l, 16, 0, 17);
}
__device__ __forceinline__ void store_h16(void* p, float v) {
    _Float16 h = (_Float16)v;
    unsigned short us;
    __builtin_memcpy(&us, &h, 2);
    unsigned int uu = us;
    asm volatile("global_store_short %0, %1, off sc0 sc1" :: "v"(p), "v"(uu) : "memory");
}

// ---------------------------------------------------------------------------
// prep: x (B,L,C) -> xs_seg, xt_seg fp32 (step, n, seg); channel-axis moving
// mean (reference semantics), window 25, edge replication.
// ---------------------------------------------------------------------------
__global__ __launch_bounds__(256) void prep_kernel(const float* __restrict__ x,
                                                   float* __restrict__ xs_seg,
                                                   float* __restrict__ xt_seg) {
    int b = blockIdx.x >> 2;
    int t = ((blockIdx.x & 3) << 8) + threadIdx.x;
    const float* xb    = x + (size_t)b * (L_ * C_);
    const float* xrow  = xb + (size_t)t * C_;
    const float* xlast = xb + (size_t)(L_ - 1) * C_;

    float diff[C_];
#pragma unroll
    for (int c = 0; c < C_; ++c) diff[c] = xrow[c] - xlast[c];
    float ps[C_ + 1];
    ps[0] = 0.f;
#pragma unroll
    for (int c = 0; c < C_; ++c) ps[c + 1] = ps[c] + diff[c];

    int s = t >> 4, q = t & 15;
#pragma unroll
    for (int c = 0; c < C_; ++c) {
        int lo = c - 12, hi = c + 12;
        float sum = ps[(hi < 31 ? hi : 31) + 1] - ps[lo > 0 ? lo : 0];
        if (lo < 0)  sum += (float)(-lo)     * diff[0];
        if (hi > 31) sum += (float)(hi - 31) * diff[31];
        float mean = sum * (1.0f / 25.0f);
        size_t idx = ((size_t)s * N_ + (size_t)(b * C_ + c)) * SEG_ + q;
        xt_seg[idx] = mean;
        xs_seg[idx] = diff[c] - mean;
    }
}

// ---------------------------------------------------------------------------
// emb batch: emb_buf[sl][gru][n][512] f16 = relu(xseg @ W_emb^T + b_emb)
// ---------------------------------------------------------------------------
__global__ __launch_bounds__(256) void emb_kernel(
    const float* __restrict__ xs_seg, const float* __restrict__ xt_seg,
    const float* __restrict__ W_emb, const float* __restrict__ b_emb,
    _Float16* __restrict__ emb_buf, int s0) {
    int bid = blockIdx.x;
    int gru = bid >> 8, sl = (bid >> 4) & 15, nch = bid & 15;
    int step = s0 + sl, n0 = nch * 64;
    const float* xseg = gru ? xt_seg : xs_seg;
    __shared__ float xl[64 * 16];
    int tid = threadIdx.x;
    const float* src = xseg + ((size_t)step * N_ + n0) * SEG_;
    for (int i = tid; i < 1024; i += 256) xl[i] = src[i];

    int kg = tid & 127;
    int rh = tid >> 7;
    float w[4][16], bb[4];
#pragma unroll
    for (int i = 0; i < 4; ++i) {
        int k = kg * 4 + i;
        const float4* wr = (const float4*)(W_emb + (size_t)k * 16);
#pragma unroll
        for (int v = 0; v < 4; ++v) {
            float4 tt = wr[v];
            w[i][v * 4 + 0] = tt.x; w[i][v * 4 + 1] = tt.y;
            w[i][v * 4 + 2] = tt.z; w[i][v * 4 + 3] = tt.w;
        }
        bb[i] = b_emb[k];
    }
    __syncthreads();
    _Float16* dst = emb_buf + ((size_t)(sl * 2 + gru) * N_ + n0) * D_ + kg * 4;
    for (int r = 0; r < 32; ++r) {
        int row = rh * 32 + r;
        float a0 = bb[0], a1 = bb[1], a2 = bb[2], a3 = bb[3];
#pragma unroll
        for (int q = 0; q < 16; ++q) {
            float xv = xl[row * 16 + q];
            a0 = fmaf(xv, w[0][q], a0);
            a1 = fmaf(xv, w[1][q], a1);
            a2 = fmaf(xv, w[2][q], a2);
            a3 = fmaf(xv, w[3][q], a3);
        }
        f16x4 v;
        v[0] = (_Float16)(a0 > 0.f ? a0 : 0.f);
        v[1] = (_Float16)(a1 > 0.f ? a1 : 0.f);
        v[2] = (_Float16)(a2 > 0.f ? a2 : 0.f);
        v[3] = (_Float16)(a3 > 0.f ? a3 : 0.f);
        *(f16x4*)(dst + (size_t)row * D_) = v;
    }
}

// ---------------------------------------------------------------------------
// pack Wih -> [gru][kt 16][gc 1536][32 k] f16.
// gc -> j map (shared with chain): member=gc/192, wn=(gc%192)/48,
// gate=(gc%48)/16, jl=gc&15, j = member*64 + wn*16 + jl.
// ---------------------------------------------------------------------------
__global__ __launch_bounds__(256) void pack_wih_kernel(
    const float* __restrict__ Wih_s, const float* __restrict__ Wih_t,
    _Float16* __restrict__ wp) {
    int e = blockIdx.x * 256 + threadIdx.x;     // 2*16*1536*32
    int kk = e & 31;
    int t = e >> 5;
    int gc = t % 1536;
    int t2 = t / 1536;
    int kt = t2 & 15, gru = t2 >> 4;
    int member = gc / 192, r = gc % 192;
    int wn = r / 48, r2 = r % 48;
    int gate = r2 >> 4, jl = r2 & 15;
    int j = member * 64 + wn * 16 + jl;
    int k = kt * 32 + kk;
    const float* W = gru ? Wih_t : Wih_s;
    wp[e] = (_Float16)W[(size_t)(gate * 512 + j) * 512 + k];
}

// ---------------------------------------------------------------------------
// pack Whh pre-swizzled for chain: [gru][m 8][kt 4][chunk 3072][8 f16]
// chunk c: gc=c>>4, s=c&15, q=s^(gc&15); k = kt*128 + q*8 + fi;
// gc = wn*48+gate*16+jl, j = member*64+wn*16+jl.
// ---------------------------------------------------------------------------
__global__ __launch_bounds__(256) void pack_whh5_kernel(
    const float* __restrict__ Whh_s, const float* __restrict__ Whh_t,
    _Float16* __restrict__ wp) {
    int e = blockIdx.x * 256 + threadIdx.x;     // 2*8*4*3072*8 = 1572864
    int fi = e & 7;
    int t = e >> 3;
    int c = t % 3072;
    int t2 = t / 3072;
    int kt = t2 & 3;
    int t3 = t2 >> 2;
    int member = t3 & 7, gru = t3 >> 3;
    int gc = c >> 4, s = c & 15;
    int q = s ^ (gc & 15);
    int k = kt * 128 + q * 8 + fi;
    int wn = gc / 48, r2 = gc % 48;
    int gate = r2 >> 4, jl = r2 & 15;
    int j = member * 64 + wn * 16 + jl;
    const float* W = gru ? Whh_t : Whh_s;
    wp[e] = (_Float16)W[(size_t)(gate * 512 + j) * 512 + k];
}

// pe[gru][n][512] f16
__global__ __launch_bounds__(256) void pack_pe_kernel(
    const float* __restrict__ pos_s, const float* __restrict__ ch_s,
    const float* __restrict__ pos_t, const float* __restrict__ ch_t,
    _Float16* __restrict__ pe) {
    int e = blockIdx.x * 256 + threadIdx.x;     // 2*1024*512
    int k = e & 511;
    int n = (e >> 9) & 1023;
    int gru = e >> 19;
    int c = n & 31;
    const float* pos = gru ? pos_t : pos_s;
    const float* ch  = gru ? ch_t  : ch_s;
    float v = (k < 256) ? pos[k] : ch[c * 256 + (k - 256)];
    pe[e] = (_Float16)v;
}

// ---------------------------------------------------------------------------
// gi GEMM (R5 body). Output layout: [sl][gru][member 8][Mt 16][tid 512][24]
// — each chain-kernel consumer thread's 24 gate values contiguous (48 B).
// Mt = x&7 pins XCD for Wih-pack L2 residency.
// ---------------------------------------------------------------------------
__global__ __launch_bounds__(512, 2) void gi_gemm_kernel(
    const _Float16* __restrict__ emb, const _Float16* __restrict__ pe,
    const _Float16* __restrict__ wih_pack,
    _Float16* __restrict__ gi, _Float16* __restrict__ gi_pe, int mode) {
    __shared__ __align__(16) char sA[8192];
    __shared__ __align__(16) char sB[16384];
    int Mt = blockIdx.x & 7, Nt = blockIdx.x >> 3;
    int sl = blockIdx.y, gru = blockIdx.z;
    int tid = threadIdx.x, w = tid >> 6, lane = tid & 63;
    int wm = w & 3, wn = w >> 2, ml = lane & 15, qq = lane >> 4;

    const char* Ab = mode ? (const char*)(pe  + (size_t)gru * N_ * D_)
                          : (const char*)(emb + (size_t)(sl * 2 + gru) * N_ * D_);
    const char* Bb = (const char*)wih_pack + (size_t)(gru * 16) * 1536 * 64;

    int cA = tid;
    int rA = cA >> 2, kqA = (cA & 3) ^ ((rA >> 1) & 3);
    const char* gA = Ab + (size_t)(Mt * 128 + rA) * 1024 + kqA * 16;
    int cB0 = tid, cB1 = 512 + tid;
    int rB0 = cB0 >> 2, kqB0 = (cB0 & 3) ^ ((rB0 >> 1) & 3);
    int rB1 = cB1 >> 2, kqB1 = (cB1 & 3) ^ ((rB1 >> 1) & 3);

    int offA[2], offB[8];
#pragma unroll
    for (int mf = 0; mf < 2; ++mf) {
        int row = wm * 32 + mf * 16 + ml;
        offA[mf] = (row * 4 + (qq ^ ((row >> 1) & 3))) * 16;
    }
#pragma unroll
    for (int nf = 0; nf < 8; ++nf) {
        int gc = wn * 128 + nf * 16 + ml;
        offB[nf] = (gc * 4 + (qq ^ ((gc >> 1) & 3))) * 16;
    }

    f32x4 acc[2][8];
#pragma unroll
    for (int i = 0; i < 2; ++i)
#pragma unroll
        for (int nf = 0; nf < 8; ++nf) {
            f32x4 z = {0.f, 0.f, 0.f, 0.f};
            acc[i][nf] = z;
        }

    for (int kt = 0; kt < 16; ++kt) {
        __syncthreads();
        stage16(gA + kt * 64, sA + w * 1024);
        const char* Bkt = Bb + (size_t)kt * 98304 + (size_t)Nt * 16384;
        stage16(Bkt + rB0 * 64 + kqB0 * 16, sB + w * 1024);
        stage16(Bkt + rB1 * 64 + kqB1 * 16, sB + 8192 + w * 1024);
        asm volatile("s_waitcnt vmcnt(0)" ::: "memory");
        __syncthreads();
        f16x8 a0 = *(const f16x8*)(sA + offA[0]);
        f16x8 a1 = *(const f16x8*)(sA + offA[1]);
#pragma unroll
        for (int nf = 0; nf < 8; ++nf) {
            f16x8 b = *(const f16x8*)(sB + offB[nf]);
            acc[0][nf] = __builtin_amdgcn_mfma_f32_16x16x32_f16(a0, b, acc[0][nf], 0, 0, 0);
            acc[1][nf] = __builtin_amdgcn_mfma_f32_16x16x32_f16(a1, b, acc[1][nf], 0, 0, 0);
        }
    }

    _Float16* ob = mode ? gi_pe + (size_t)gru * 8 * 16 * 512 * 24
                        : gi    + (size_t)(sl * 2 + gru) * 8 * 16 * 512 * 24;
#pragma unroll
    for (int nf = 0; nf < 8; ++nf) {
        int gcg = Nt * 256 + wn * 128 + nf * 16 + ml;
        int member = gcg / 192, r = gcg % 192;
        int wn_c = r / 48, r2 = r % 48;
        int gate = r2 >> 4, ml_c = r2 & 15;
#pragma unroll
        for (int mf = 0; mf < 2; ++mf)
#pragma unroll
            for (int reg = 0; reg < 4; ++reg) {
                int row_g = Mt * 128 + wm * 32 + mf * 16 + qq * 4 + reg;
                int Mt_c = row_g >> 6, rowL = row_g & 63;
                int wm_c = rowL >> 5, rt = (rowL >> 4) & 1;
                int qq_c = (rowL >> 2) & 3, reg_c = rowL & 3;
                int tid_c = (wn_c * 2 + wm_c) * 64 + qq_c * 16 + ml_c;
                int v = rt * 12 + reg_c * 3 + gate;
                ob[((size_t)member * 16 + Mt_c) * 512 * 24 + tid_c * 24 + v]
                    = (_Float16)acc[mf][nf][reg];
            }
    }
}

// ---------------------------------------------------------------------------
// Persistent chain scan: 256 blocks (1/CU) x 512 thr. 32 chains (Mt,gru),
// 8 members; member owns 64 j-cols (192 gc). BK=128 (4 kt), XOR-16 swizzle.
// B (Whh) LDS double-buffer with alternating K-direction per step -> only
// 2 of 4 B-tiles restaged per step. gi read direct global->VGPR (thread-
// packed layout, no LDS). h exchange via sc0/sc1, per-chain monotone barrier.
// NOTE: fetch_add is UNCONDITIONAL (every step, incl. the last of a launch);
// only the spin is gated — R8's conditional add desynced the monotone
// counter across launches and deadlocked to the guard bail.
// ---------------------------------------------------------------------------
__global__ __launch_bounds__(512) void gru_chain_kernel(
    const _Float16* __restrict__ whh_pk5,  // [gru][m8][kt4][3072][8]
    const _Float16* __restrict__ gi_base,  // [it][gru][m8][Mt16][512][24]
    const float* __restrict__ bih_s, const float* __restrict__ bhh_s,
    const float* __restrict__ bih_t, const float* __restrict__ bhh_t,
    _Float16* __restrict__ hbf0, _Float16* __restrict__ hbf1,
    unsigned* __restrict__ flags, int nsteps, int sbase) {
    __shared__ __align__(16) char sA[2][16384];
    __shared__ __align__(16) char sB[2][49152];
    int bid = blockIdx.x;
    int member = bid & 7, chain = bid >> 3;
    int Mt = chain & 15, gru = chain >> 4;
    int tid = threadIdx.x, w = tid >> 6, lane = tid & 63;
    int ml = lane & 15, qq = lane >> 4;
    int wm = w & 1, wn = w >> 1;

    const char* Bb = (const char*)whh_pk5 + (size_t)(gru * 8 + member) * 196608;
    const char* h0 = (const char*)hbf0 + ((size_t)gru * N_ + Mt * 64) * 1024;
    const char* h1 = (const char*)hbf1 + ((size_t)gru * N_ + Mt * 64) * 1024;

    // A staging map (2 calls of 512 chunks)
    int aRow[2], aQ[2];
#pragma unroll
    for (int r = 0; r < 2; ++r) {
        int c = r * 512 + tid;
        aRow[r] = c >> 4;
        aQ[r] = (c & 15) ^ (aRow[r] & 15);
    }

    // fragment offsets
    int offA[2][4], offB[3][4];
#pragma unroll
    for (int rt = 0; rt < 2; ++rt) {
        int row = wm * 32 + rt * 16 + ml;
#pragma unroll
        for (int kf = 0; kf < 4; ++kf)
            offA[rt][kf] = row * 256 + ((kf * 4 + qq) ^ (row & 15)) * 16;
    }
#pragma unroll
    for (int g = 0; g < 3; ++g) {
        int gc = wn * 48 + g * 16 + ml;
#pragma unroll
        for (int kf = 0; kf < 4; ++kf)
            offB[g][kf] = gc * 256 + ((kf * 4 + qq) ^ (gc & 15)) * 16;
    }

    // biases + register-resident hp
    const float* bi = gru ? bih_t : bih_s;
    const float* bh = gru ? bhh_t : bhh_s;
    int j = member * 64 + wn * 16 + ml;
    float bir = bi[j], biz = bi[D_ + j], bin = bi[2 * D_ + j];
    float bhr = bh[j], bhz = bh[D_ + j], bhn = bh[2 * D_ + j];
    float hp[2][4];
#pragma unroll
    for (int rt = 0; rt < 2; ++rt)
#pragma unroll
        for (int reg = 0; reg < 4; ++reg) {
            int row = Mt * 64 + wm * 32 + rt * 16 + qq * 4 + reg;
            hp[rt][reg] = (float)hbf0[((size_t)gru * N_ + row) * D_ + j];
        }

    unsigned* flag = flags + chain * 32;

    // gi pointer for a given it
    const _Float16* giTid0 = gi_base
        + (((size_t)gru * 8 + member) * 16 + Mt) * 512 * 24 + (size_t)tid * 24;
    size_t giStep = (size_t)2 * 8 * 16 * 512 * 24;

    int dir0 = sbase & 1;   // 0 (all our sbase are even)

    // ---- prologue: gi(it0) + B ktseq0,1 + A ktseq0,1 ----
    f16x8 gv0, gv1, gv2;
    {
        const _Float16* gp = giTid0;
        gv0 = *(const f16x8*)(gp);
        gv1 = *(const f16x8*)(gp + 8);
        gv2 = *(const f16x8*)(gp + 16);
        const char* hin = dir0 ? h1 : h0;
#pragma unroll
        for (int s = 0; s < 2; ++s) {       // ktseq0 = 0, ktseq1 = 1 (forward)
            int kt = s;
            const char* Bkt = Bb + kt * 49152;
#pragma unroll
            for (int r = 0; r < 6; ++r)
                stage16(Bkt + (size_t)(r * 512 + tid) * 16,
                        sB[kt & 1] + r * 8192 + w * 1024);
        }
#pragma unroll
        for (int s = 0; s < 2; ++s) {
            int kt = s;
#pragma unroll
            for (int r = 0; r < 2; ++r)
                stage16c(hin + (size_t)aRow[r] * 1024 + kt * 256 + aQ[r] * 16,
                         sA[s & 1] + r * 8192 + w * 1024);
        }
    }

    for (int it = 0; it < nsteps; ++it) {
        int gstep = sbase + it;
        int dir = gstep & 1;
        const char* hin = (gstep & 1) ? h1 : h0;
        _Float16* hout = (gstep & 1) ? hbf0 : hbf1;

        f32x4 acc[2][3];
#pragma unroll
        for (int rt = 0; rt < 2; ++rt)
#pragma unroll
            for (int g = 0; g < 3; ++g) {
                f32x4 z = {0.f, 0.f, 0.f, 0.f};
                acc[rt][g] = z;
            }

        for (int i = 0; i < 4; ++i) {
            int kt = dir ? 3 - i : i;
            __syncthreads();
            if (i == 1 || i == 2) {
                int ktn = dir ? 3 - (i + 1) : (i + 1);
                const char* Bkt = Bb + ktn * 49152;
#pragma unroll
                for (int r = 0; r < 6; ++r)
                    stage16(Bkt + (size_t)(r * 512 + tid) * 16,
                            sB[ktn & 1] + r * 8192 + w * 1024);
#pragma unroll
                for (int r = 0; r < 2; ++r)
                    stage16c(hin + (size_t)aRow[r] * 1024 + ktn * 256 + aQ[r] * 16,
                             sA[(i + 1) & 1] + r * 8192 + w * 1024);
                asm volatile("s_waitcnt vmcnt(8)" ::: "memory");
            } else if (i == 0) {
                asm volatile("s_waitcnt vmcnt(2)" ::: "memory");
            } else {
                asm volatile("s_waitcnt vmcnt(0)" ::: "memory");
            }
            __syncthreads();
            const char* cA = sA[i & 1];
            const char* cB = sB[kt & 1];
            f16x8 a0[4], a1[4];
#pragma unroll
            for (int kf = 0; kf < 4; ++kf) {
                a0[kf] = *(const f16x8*)(cA + offA[0][kf]);
                a1[kf] = *(const f16x8*)(cA + offA[1][kf]);
            }
#pragma unroll
            for (int g = 0; g < 3; ++g)
#pragma unroll
                for (int kf = 0; kf < 4; ++kf) {
                    f16x8 b = *(const f16x8*)(cB + offB[g][kf]);
                    acc[0][g] = __builtin_amdgcn_mfma_f32_16x16x32_f16(a0[kf], b, acc[0][g], 0, 0, 0);
                    acc[1][g] = __builtin_amdgcn_mfma_f32_16x16x32_f16(a1[kf], b, acc[1][g], 0, 0, 0);
                }
        }

        // ---- fused GRU epilogue (gi from VGPRs) ----
#pragma unroll
        for (int rt = 0; rt < 2; ++rt)
#pragma unroll
            for (int reg = 0; reg < 4; ++reg) {
                int v0 = rt * 12 + reg * 3;
                float gr = (float)((v0 + 0) < 8 ? gv0[(v0 + 0) & 7]
                          : ((v0 + 0) < 16 ? gv1[(v0 + 0) & 7] : gv2[(v0 + 0) & 7]));
                float gz = (float)((v0 + 1) < 8 ? gv0[(v0 + 1) & 7]
                          : ((v0 + 1) < 16 ? gv1[(v0 + 1) & 7] : gv2[(v0 + 1) & 7]));
                float gn = (float)((v0 + 2) < 8 ? gv0[(v0 + 2) & 7]
                          : ((v0 + 2) < 16 ? gv1[(v0 + 2) & 7] : gv2[(v0 + 2) & 7]));
                int row = Mt * 64 + wm * 32 + rt * 16 + qq * 4 + reg;
                float r = 1.f / (1.f + __expf(-(acc[rt][0][reg] + gr + bir + bhr)));
                float z = 1.f / (1.f + __expf(-(acc[rt][1][reg] + gz + biz + bhz)));
                float nn = tanhf(gn + bin + r * (acc[rt][2][reg] + bhn));
                float hv = (1.f - z) * nn + z * hp[rt][reg];
                hp[rt][reg] = hv;
                store_h16(hout + ((size_t)gru * N_ + row) * D_ + j, hv);
            }

        asm volatile("s_waitcnt vmcnt(0)" ::: "memory");   // drain h stores
        __syncthreads();
        if (tid == 0) {
            // UNCONDITIONAL add — keeps the monotone counter consistent
            // across launches (R8 bug: add was inside the if -> deadlock).
            __hip_atomic_fetch_add(flag, 1u, __ATOMIC_RELAXED, __HIP_MEMORY_SCOPE_AGENT);
            if (it < nsteps - 1) {
                unsigned tgt = 8u * (unsigned)(gstep + 1);
                int guard = 0;
                while (__hip_atomic_load(flag, __ATOMIC_RELAXED, __HIP_MEMORY_SCOPE_AGENT) < tgt) {
                    __builtin_amdgcn_s_sleep(1);
                    if (++guard > (1 << 22)) break;   // bail: fail, don't hang
                }
            }
        }
        if (it < nsteps - 1) {
            // prefetch next step's gi (no h dependency)
            const _Float16* gp = giTid0 + (size_t)(it + 1) * giStep;
            gv0 = *(const f16x8*)(gp);
            gv1 = *(const f16x8*)(gp + 8);
            gv2 = *(const f16x8*)(gp + 16);
            __syncthreads();
            // post-barrier: stage A ktseq0,1 of next step (B already resident)
            int dirn = (gstep + 1) & 1;
            const char* hinN = dirn ? h1 : h0;
#pragma unroll
            for (int s = 0; s < 2; ++s) {
                int kt = dirn ? 3 - s : s;
#pragma unroll
                for (int r = 0; r < 2; ++r)
                    stage16c(hinN + (size_t)aRow[r] * 1024 + kt * 256 + aQ[r] * 16,
                             sA[s & 1] + r * 8192 + w * 1024);
            }
        }
    }
}

// ---------------------------------------------------------------------------
__global__ __launch_bounds__(256) void head_kernel(
    const _Float16* __restrict__ hs2, const _Float16* __restrict__ ht2,
    const float* __restrict__ Wps, const float* __restrict__ bps,
    const float* __restrict__ Wpt, const float* __restrict__ bpt,
    const float* __restrict__ x, float* __restrict__ out) {
    int g = blockIdx.x * 256 + threadIdx.x;
    int n = g >> 4, p = g & 15;
    int b = n >> 5, c = n & 31;
    const _Float16* hs = hs2 + (size_t)n * D_;
    const _Float16* ht = ht2 + (size_t)n * D_;
    const float* ws = Wps + (size_t)p * D_;
    const float* wt = Wpt + (size_t)p * D_;
    float acc = bps[p] + bpt[p];
    for (int k = 0; k < D_; ++k)
        acc += (float)hs[k] * ws[k] + (float)ht[k] * wt[k];
    float last = x[((size_t)b * L_ + (L_ - 1)) * C_ + c];
    out[((size_t)b * SEG_ + p) * C_ + c] = acc + last;
}

// ---------------------------------------------------------------------------
extern "C" void kernel_launch(void* const* d_in, const int* in_sizes, int n_in,
                              void* d_out, int out_size, void* d_ws, size_t ws_size,
                              hipStream_t stream) {
    const float* x     = (const float*)d_in[0];
    const float* W_emb = (const float*)d_in[1];
    const float* b_emb = (const float*)d_in[2];
    const float* Wih_s = (const float*)d_in[3];
    const float* Whh_s = (const float*)d_in[4];
    const float* bih_s = (const float*)d_in[5];
    const float* bhh_s = (const float*)d_in[6];
    const float* Wih_t = (const float*)d_in[7];
    const float* Whh_t = (const float*)d_in[8];
    const float* bih_t = (const float*)d_in[9];
    const float* bhh_t = (const float*)d_in[10];
    const float* pos_s = (const float*)d_in[11];
    const float* ch_s  = (const float*)d_in[12];
    const float* pos_t = (const float*)d_in[13];
    const float* ch_t  = (const float*)d_in[14];
    const float* Wps   = (const float*)d_in[15];
    const float* bps   = (const float*)d_in[16];
    const float* Wpt   = (const float*)d_in[17];
    const float* bpt   = (const float*)d_in[18];
    float* out = (float*)d_out;

    char* p = (char*)d_ws;
    float* xs_seg = (float*)p;          p += (size_t)SX_ * N_ * SEG_ * 4;        // 4 MB
    float* xt_seg = (float*)p;          p += (size_t)SX_ * N_ * SEG_ * 4;        // 4 MB
    _Float16* emb_buf = (_Float16*)p;   p += (size_t)16 * 2 * N_ * D_ * 2;       // 32 MB
    _Float16* gi_buf  = (_Float16*)p;   p += (size_t)16 * 2 * 8 * 16 * 512 * 24 * 2; // 96 MB
    _Float16* gi_pe   = (_Float16*)p;   p += (size_t)2 * 8 * 16 * 512 * 24 * 2;  // 6 MB
    _Float16* pe_buf  = (_Float16*)p;   p += (size_t)2 * N_ * D_ * 2;            // 2 MB
    _Float16* wih_pk  = (_Float16*)p;   p += (size_t)2 * 16 * 1536 * 32 * 2;     // 3 MB
    _Float16* whh_pk5 = (_Float16*)p;   p += (size_t)2 * 8 * 4 * 3072 * 8 * 2;   // 3 MB
    _Float16* hbf0 = (_Float16*)p;      p += (size_t)2 * N_ * D_ * 2;            // 2 MB
    _Float16* hbf1 = (_Float16*)p;      p += (size_t)2 * N_ * D_ * 2;            // 2 MB
    unsigned* flags = (unsigned*)p;     p += 32 * 32 * 4;                        // 4 KB

    hipMemsetAsync(hbf0, 0, (size_t)2 * N_ * D_ * 2, stream);
    hipMemsetAsync(flags, 0, 32 * 32 * 4, stream);

    pack_wih_kernel<<<6144, 256, 0, stream>>>(Wih_s, Wih_t, wih_pk);
    pack_whh5_kernel<<<6144, 256, 0, stream>>>(Whh_s, Whh_t, whh_pk5);
    pack_pe_kernel<<<4096, 256, 0, stream>>>(pos_s, ch_s, pos_t, ch_t, pe_buf);
    prep_kernel<<<B_ * 4, 256, 0, stream>>>(x, xs_seg, xt_seg);

    for (int b = 0; b < 4; ++b) {
        emb_kernel<<<512, 256, 0, stream>>>(xs_seg, xt_seg, W_emb, b_emb, emb_buf, b * 16);
        gi_gemm_kernel<<<dim3(48, 16, 2), 512, 0, stream>>>(
            emb_buf, pe_buf, wih_pk, gi_buf, gi_pe, 0);
        gru_chain_kernel<<<256, 512, 0, stream>>>(
            whh_pk5, gi_buf, bih_s, bhh_s, bih_t, bhh_t,
            hbf0, hbf1, flags, 16, b * 16);
    }
    // decoder: gi from pe, one step (hbf0 -> hbf1)
    gi_gemm_kernel<<<dim3(48, 1, 2), 512, 0, stream>>>(
        emb_buf, pe_buf, wih_pk, gi_buf, gi_pe, 1);
    gru_chain_kernel<<<256, 512, 0, stream>>>(
        whh_pk5, gi_pe, bih_s, bhh_s, bih_t, bhh_t,
        hbf0, hbf1, flags, 1, 64);

    head_kernel<<<N_ * SEG_ / 256, 256, 0, stream>>>(
        hbf1, hbf1 + (size_t)N_ * D_, Wps, bps, Wpt, bpt, x, out);
}

// Round 10
// 925.449 us; speedup vs baseline: 1.6824x; 1.6824x over previous
//
#include <hip/hip_runtime.h>
#include <math.h>

#define B_   32
#define L_   1024
#define C_   32
#define D_   512
#define SEG_ 16
#define SX_  64
#define N_   1024   // B*C

typedef _Float16 f16x8 __attribute__((ext_vector_type(8)));
typedef _Float16 f16x4 __attribute__((ext_vector_type(4)));
typedef float    f32x4 __attribute__((ext_vector_type(4)));

__device__ __forceinline__ void stage16(const void* g, void* l) {
    __builtin_amdgcn_global_load_lds((const __attribute__((address_space(1))) void*)g,
                                     (__attribute__((address_space(3))) void*)l, 16, 0, 0);
}
// sc0|sc1: device-coherent (coherence-point) load -> LDS, cross-XCD safe
__device__ __forceinline__ void stage16c(const void* g, void* l) {
    __builtin_amdgcn_global_load_lds((const __attribute__((address_space(1))) void*)g,
                                     (__attribute__((address_space(3))) void*)l, 16, 0, 17);
}
__device__ __forceinline__ void store_h16(void* p, float v) {
    _Float16 h = (_Float16)v;
    unsigned short us;
    __builtin_memcpy(&us, &h, 2);
    unsigned int uu = us;
    asm volatile("global_store_short %0, %1, off sc0 sc1" :: "v"(p), "v"(uu) : "memory");
}

// ---------------------------------------------------------------------------
// prep: x (B,L,C) -> xs_seg, xt_seg fp32 (step, n, seg); channel-axis moving
// mean (reference semantics), window 25, edge replication.
// ---------------------------------------------------------------------------
__global__ __launch_bounds__(256) void prep_kernel(const float* __restrict__ x,
                                                   float* __restrict__ xs_seg,
                                                   float* __restrict__ xt_seg) {
    int b = blockIdx.x >> 2;
    int t = ((blockIdx.x & 3) << 8) + threadIdx.x;
    const float* xb    = x + (size_t)b * (L_ * C_);
    const float* xrow  = xb + (size_t)t * C_;
    const float* xlast = xb + (size_t)(L_ - 1) * C_;

    float diff[C_];
#pragma unroll
    for (int c = 0; c < C_; ++c) diff[c] = xrow[c] - xlast[c];
    float ps[C_ + 1];
    ps[0] = 0.f;
#pragma unroll
    for (int c = 0; c < C_; ++c) ps[c + 1] = ps[c] + diff[c];

    int s = t >> 4, q = t & 15;
#pragma unroll
    for (int c = 0; c < C_; ++c) {
        int lo = c - 12, hi = c + 12;
        float sum = ps[(hi < 31 ? hi : 31) + 1] - ps[lo > 0 ? lo : 0];
        if (lo < 0)  sum += (float)(-lo)     * diff[0];
        if (hi > 31) sum += (float)(hi - 31) * diff[31];
        float mean = sum * (1.0f / 25.0f);
        size_t idx = ((size_t)s * N_ + (size_t)(b * C_ + c)) * SEG_ + q;
        xt_seg[idx] = mean;
        xs_seg[idx] = diff[c] - mean;
    }
}

// ---------------------------------------------------------------------------
// emb batch: emb_buf[sl][gru][n][512] f16 = relu(xseg @ W_emb^T + b_emb)
// ---------------------------------------------------------------------------
__global__ __launch_bounds__(256) void emb_kernel(
    const float* __restrict__ xs_seg, const float* __restrict__ xt_seg,
    const float* __restrict__ W_emb, const float* __restrict__ b_emb,
    _Float16* __restrict__ emb_buf, int s0) {
    int bid = blockIdx.x;
    int gru = bid >> 8, sl = (bid >> 4) & 15, nch = bid & 15;
    int step = s0 + sl, n0 = nch * 64;
    const float* xseg = gru ? xt_seg : xs_seg;
    __shared__ float xl[64 * 16];
    int tid = threadIdx.x;
    const float* src = xseg + ((size_t)step * N_ + n0) * SEG_;
    for (int i = tid; i < 1024; i += 256) xl[i] = src[i];

    int kg = tid & 127;
    int rh = tid >> 7;
    float w[4][16], bb[4];
#pragma unroll
    for (int i = 0; i < 4; ++i) {
        int k = kg * 4 + i;
        const float4* wr = (const float4*)(W_emb + (size_t)k * 16);
#pragma unroll
        for (int v = 0; v < 4; ++v) {
            float4 tt = wr[v];
            w[i][v * 4 + 0] = tt.x; w[i][v * 4 + 1] = tt.y;
            w[i][v * 4 + 2] = tt.z; w[i][v * 4 + 3] = tt.w;
        }
        bb[i] = b_emb[k];
    }
    __syncthreads();
    _Float16* dst = emb_buf + ((size_t)(sl * 2 + gru) * N_ + n0) * D_ + kg * 4;
    for (int r = 0; r < 32; ++r) {
        int row = rh * 32 + r;
        float a0 = bb[0], a1 = bb[1], a2 = bb[2], a3 = bb[3];
#pragma unroll
        for (int q = 0; q < 16; ++q) {
            float xv = xl[row * 16 + q];
            a0 = fmaf(xv, w[0][q], a0);
            a1 = fmaf(xv, w[1][q], a1);
            a2 = fmaf(xv, w[2][q], a2);
            a3 = fmaf(xv, w[3][q], a3);
        }
        f16x4 v;
        v[0] = (_Float16)(a0 > 0.f ? a0 : 0.f);
        v[1] = (_Float16)(a1 > 0.f ? a1 : 0.f);
        v[2] = (_Float16)(a2 > 0.f ? a2 : 0.f);
        v[3] = (_Float16)(a3 > 0.f ? a3 : 0.f);
        *(f16x4*)(dst + (size_t)row * D_) = v;
    }
}

// ---------------------------------------------------------------------------
// pack Wih -> [gru][kt 16][gc 1536][32 k] f16.
// gc -> j map (shared with chain): member=gc/192, wn=(gc%192)/48,
// gate=(gc%48)/16, jl=gc&15, j = member*64 + wn*16 + jl.
// ---------------------------------------------------------------------------
__global__ __launch_bounds__(256) void pack_wih_kernel(
    const float* __restrict__ Wih_s, const float* __restrict__ Wih_t,
    _Float16* __restrict__ wp) {
    int e = blockIdx.x * 256 + threadIdx.x;     // 2*16*1536*32
    int kk = e & 31;
    int t = e >> 5;
    int gc = t % 1536;
    int t2 = t / 1536;
    int kt = t2 & 15, gru = t2 >> 4;
    int member = gc / 192, r = gc % 192;
    int wn = r / 48, r2 = r % 48;
    int gate = r2 >> 4, jl = r2 & 15;
    int j = member * 64 + wn * 16 + jl;
    int k = kt * 32 + kk;
    const float* W = gru ? Wih_t : Wih_s;
    wp[e] = (_Float16)W[(size_t)(gate * 512 + j) * 512 + k];
}

// ---------------------------------------------------------------------------
// pack Whh pre-swizzled for chain: [gru][m 8][kt 4][chunk 3072][8 f16]
// chunk c: gc=c>>4, s=c&15, q=s^(gc&15); k = kt*128 + q*8 + fi;
// gc = wn*48+gate*16+jl, j = member*64+wn*16+jl.
// ---------------------------------------------------------------------------
__global__ __launch_bounds__(256) void pack_whh5_kernel(
    const float* __restrict__ Whh_s, const float* __restrict__ Whh_t,
    _Float16* __restrict__ wp) {
    int e = blockIdx.x * 256 + threadIdx.x;     // 2*8*4*3072*8 = 1572864
    int fi = e & 7;
    int t = e >> 3;
    int c = t % 3072;
    int t2 = t / 3072;
    int kt = t2 & 3;
    int t3 = t2 >> 2;
    int member = t3 & 7, gru = t3 >> 3;
    int gc = c >> 4, s = c & 15;
    int q = s ^ (gc & 15);
    int k = kt * 128 + q * 8 + fi;
    int wn = gc / 48, r2 = gc % 48;
    int gate = r2 >> 4, jl = r2 & 15;
    int j = member * 64 + wn * 16 + jl;
    const float* W = gru ? Whh_t : Whh_s;
    wp[e] = (_Float16)W[(size_t)(gate * 512 + j) * 512 + k];
}

// pe[gru][n][512] f16
__global__ __launch_bounds__(256) void pack_pe_kernel(
    const float* __restrict__ pos_s, const float* __restrict__ ch_s,
    const float* __restrict__ pos_t, const float* __restrict__ ch_t,
    _Float16* __restrict__ pe) {
    int e = blockIdx.x * 256 + threadIdx.x;     // 2*1024*512
    int k = e & 511;
    int n = (e >> 9) & 1023;
    int gru = e >> 19;
    int c = n & 31;
    const float* pos = gru ? pos_t : pos_s;
    const float* ch  = gru ? ch_t  : ch_s;
    float v = (k < 256) ? pos[k] : ch[c * 256 + (k - 256)];
    pe[e] = (_Float16)v;
}

// ---------------------------------------------------------------------------
// gi GEMM v3: tile 128M x 192N (Nt = consumer member, so each block owns
// whole consumer slabs [member][Mt_c=2Mt..2Mt+1]). Epilogue does an in-LDS
// transpose into the chain's thread-packed layout [..][tid 512][24] and
// issues fully-coalesced dwordx4 stores (R9's scattered 2B stores were the
// 66->225us regression). LDS tid_c slot padded to 52 B -> 2-way banks (free).
// Mt = x&7 pins XCD for Wih-pack L2 residency.
// ---------------------------------------------------------------------------
__global__ __launch_bounds__(512, 2) void gi_gemm_kernel(
    const _Float16* __restrict__ emb, const _Float16* __restrict__ pe,
    const _Float16* __restrict__ wih_pack,
    _Float16* __restrict__ gi, _Float16* __restrict__ gi_pe, int mode) {
    __shared__ __align__(16) char smem[53248];  // K-loop: A 8K + B 12K; epi: 2x26624
    char* sA = smem;
    char* sB = smem + 8192;
    int Mt = blockIdx.x & 7, Nt = blockIdx.x >> 3;   // Nt = member 0..7
    int sl = blockIdx.y, gru = blockIdx.z;
    int tid = threadIdx.x, w = tid >> 6, lane = tid & 63;
    int wm = w & 1, wn = w >> 1, ml = lane & 15, qq = lane >> 4;

    const char* Ab = mode ? (const char*)(pe  + (size_t)gru * N_ * D_)
                          : (const char*)(emb + (size_t)(sl * 2 + gru) * N_ * D_);
    const char* Bb = (const char*)wih_pack + (size_t)gru * 16 * 1536 * 64
                     + (size_t)Nt * 192 * 64;

    // A staging: 512 chunks (128 rows x 4 swizzled quads), 1/thread
    int rA = tid >> 2, kqA = (tid & 3) ^ ((rA >> 1) & 3);
    const char* gA = Ab + (size_t)(Mt * 128 + rA) * 1024 + kqA * 16;
    // B staging: 768 chunks (192 gc x 4 quads): call1 all, call2 tid<256
    int g1 = tid >> 2, kq1 = (tid & 3) ^ ((g1 >> 1) & 3);
    int c2 = 512 + tid, g2 = c2 >> 2, kq2 = (c2 & 3) ^ ((g2 >> 1) & 3);

    int offA[4], offB[3];
#pragma unroll
    for (int mf = 0; mf < 4; ++mf) {
        int row = wm * 64 + mf * 16 + ml;
        offA[mf] = (row * 4 + (qq ^ ((row >> 1) & 3))) * 16;
    }
#pragma unroll
    for (int g = 0; g < 3; ++g) {
        int gc = wn * 48 + g * 16 + ml;
        offB[g] = (gc * 4 + (qq ^ ((gc >> 1) & 3))) * 16;
    }

    f32x4 acc[4][3];
#pragma unroll
    for (int mf = 0; mf < 4; ++mf)
#pragma unroll
        for (int g = 0; g < 3; ++g) {
            f32x4 z = {0.f, 0.f, 0.f, 0.f};
            acc[mf][g] = z;
        }

    for (int kt = 0; kt < 16; ++kt) {
        __syncthreads();
        stage16(gA + kt * 64, sA + w * 1024);
        const char* Bkt = Bb + (size_t)kt * (1536 * 64);
        stage16(Bkt + g1 * 64 + kq1 * 16, sB + w * 1024);
        if (w < 4) stage16(Bkt + g2 * 64 + kq2 * 16, sB + 8192 + w * 1024);
        asm volatile("s_waitcnt vmcnt(0)" ::: "memory");
        __syncthreads();
        f16x8 a[4];
#pragma unroll
        for (int mf = 0; mf < 4; ++mf) a[mf] = *(const f16x8*)(sA + offA[mf]);
#pragma unroll
        for (int g = 0; g < 3; ++g) {
            f16x8 b = *(const f16x8*)(sB + offB[g]);
#pragma unroll
            for (int mf = 0; mf < 4; ++mf)
                acc[mf][g] = __builtin_amdgcn_mfma_f32_16x16x32_f16(a[mf], b, acc[mf][g], 0, 0, 0);
        }
    }

    // ---- epilogue: LDS transpose into consumer thread-packed layout ----
    __syncthreads();
    // scatter: slab half wm (rows wm*64..+64 == Mt_c = 2Mt+wm)
#pragma unroll
    for (int mf = 0; mf < 4; ++mf) {
        int wm_c = mf >> 1, rt = mf & 1;
        int tid_c = (wn * 2 + wm_c) * 64 + qq * 16 + ml;
        char* base = smem + wm * 26624 + tid_c * 52;
#pragma unroll
        for (int g = 0; g < 3; ++g)
#pragma unroll
            for (int reg = 0; reg < 4; ++reg) {
                int v = rt * 12 + reg * 3 + g;
                *(_Float16*)(base + v * 2) = (_Float16)acc[mf][g][reg];
            }
    }
    __syncthreads();
    _Float16* ob = mode ? gi_pe + (size_t)gru * 8 * 16 * 512 * 24
                        : gi    + (size_t)(sl * 2 + gru) * 8 * 16 * 512 * 24;
    char* obB = (char*)ob;
#pragma unroll
    for (int s = 0; s < 6; ++s) {
        int o = tid * 16 + s * 8192;           // 0..49135 logical (2 slabs x 24576)
        int mc = o / 24576;
        int o2 = o - mc * 24576;
        int tc = o2 / 48;
        int r  = o2 - tc * 48;                 // 0 / 16 / 32 (never straddles)
        const char* src = smem + mc * 26624 + tc * 52 + r;
        int4 val;
        val.x = *(const int*)(src);
        val.y = *(const int*)(src + 4);
        val.z = *(const int*)(src + 8);
        val.w = *(const int*)(src + 12);
        *(int4*)(obB + (size_t)(Nt * 16 + Mt * 2 + mc) * 24576 + o2) = val;
    }
}

// ---------------------------------------------------------------------------
// Persistent chain scan (R9, proven): 256 blocks (1/CU) x 512 thr. 32 chains,
// 8 members; member owns 64 j-cols. BK=128 (4 kt), XOR-16 swizzle, B dbuf w/
// alternating K-direction, gi direct global->VGPR, h via sc0/sc1, per-chain
// monotone barrier. fetch_add UNCONDITIONAL (R8 lesson).
// ---------------------------------------------------------------------------
__global__ __launch_bounds__(512) void gru_chain_kernel(
    const _Float16* __restrict__ whh_pk5,  // [gru][m8][kt4][3072][8]
    const _Float16* __restrict__ gi_base,  // [it][gru][m8][Mt16][512][24]
    const float* __restrict__ bih_s, const float* __restrict__ bhh_s,
    const float* __restrict__ bih_t, const float* __restrict__ bhh_t,
    _Float16* __restrict__ hbf0, _Float16* __restrict__ hbf1,
    unsigned* __restrict__ flags, int nsteps, int sbase) {
    __shared__ __align__(16) char sA[2][16384];
    __shared__ __align__(16) char sB[2][49152];
    int bid = blockIdx.x;
    int member = bid & 7, chain = bid >> 3;
    int Mt = chain & 15, gru = chain >> 4;
    int tid = threadIdx.x, w = tid >> 6, lane = tid & 63;
    int ml = lane & 15, qq = lane >> 4;
    int wm = w & 1, wn = w >> 1;

    const char* Bb = (const char*)whh_pk5 + (size_t)(gru * 8 + member) * 196608;
    const char* h0 = (const char*)hbf0 + ((size_t)gru * N_ + Mt * 64) * 1024;
    const char* h1 = (const char*)hbf1 + ((size_t)gru * N_ + Mt * 64) * 1024;

    int aRow[2], aQ[2];
#pragma unroll
    for (int r = 0; r < 2; ++r) {
        int c = r * 512 + tid;
        aRow[r] = c >> 4;
        aQ[r] = (c & 15) ^ (aRow[r] & 15);
    }

    int offA[2][4], offB[3][4];
#pragma unroll
    for (int rt = 0; rt < 2; ++rt) {
        int row = wm * 32 + rt * 16 + ml;
#pragma unroll
        for (int kf = 0; kf < 4; ++kf)
            offA[rt][kf] = row * 256 + ((kf * 4 + qq) ^ (row & 15)) * 16;
    }
#pragma unroll
    for (int g = 0; g < 3; ++g) {
        int gc = wn * 48 + g * 16 + ml;
#pragma unroll
        for (int kf = 0; kf < 4; ++kf)
            offB[g][kf] = gc * 256 + ((kf * 4 + qq) ^ (gc & 15)) * 16;
    }

    const float* bi = gru ? bih_t : bih_s;
    const float* bh = gru ? bhh_t : bhh_s;
    int j = member * 64 + wn * 16 + ml;
    float bir = bi[j], biz = bi[D_ + j], bin = bi[2 * D_ + j];
    float bhr = bh[j], bhz = bh[D_ + j], bhn = bh[2 * D_ + j];
    float hp[2][4];
#pragma unroll
    for (int rt = 0; rt < 2; ++rt)
#pragma unroll
        for (int reg = 0; reg < 4; ++reg) {
            int row = Mt * 64 + wm * 32 + rt * 16 + qq * 4 + reg;
            hp[rt][reg] = (float)hbf0[((size_t)gru * N_ + row) * D_ + j];
        }

    unsigned* flag = flags + chain * 32;

    const _Float16* giTid0 = gi_base
        + (((size_t)gru * 8 + member) * 16 + Mt) * 512 * 24 + (size_t)tid * 24;
    size_t giStep = (size_t)2 * 8 * 16 * 512 * 24;

    int dir0 = sbase & 1;

    f16x8 gv0, gv1, gv2;
    {
        const _Float16* gp = giTid0;
        gv0 = *(const f16x8*)(gp);
        gv1 = *(const f16x8*)(gp + 8);
        gv2 = *(const f16x8*)(gp + 16);
        const char* hin = dir0 ? h1 : h0;
#pragma unroll
        for (int s = 0; s < 2; ++s) {
            int kt = s;
            const char* Bkt = Bb + kt * 49152;
#pragma unroll
            for (int r = 0; r < 6; ++r)
                stage16(Bkt + (size_t)(r * 512 + tid) * 16,
                        sB[kt & 1] + r * 8192 + w * 1024);
        }
#pragma unroll
        for (int s = 0; s < 2; ++s) {
            int kt = s;
#pragma unroll
            for (int r = 0; r < 2; ++r)
                stage16c(hin + (size_t)aRow[r] * 1024 + kt * 256 + aQ[r] * 16,
                         sA[s & 1] + r * 8192 + w * 1024);
        }
    }

    for (int it = 0; it < nsteps; ++it) {
        int gstep = sbase + it;
        int dir = gstep & 1;
        const char* hin = (gstep & 1) ? h1 : h0;
        _Float16* hout = (gstep & 1) ? hbf0 : hbf1;

        f32x4 acc[2][3];
#pragma unroll
        for (int rt = 0; rt < 2; ++rt)
#pragma unroll
            for (int g = 0; g < 3; ++g) {
                f32x4 z = {0.f, 0.f, 0.f, 0.f};
                acc[rt][g] = z;
            }

        for (int i = 0; i < 4; ++i) {
            int kt = dir ? 3 - i : i;
            __syncthreads();
            if (i == 1 || i == 2) {
                int ktn = dir ? 3 - (i + 1) : (i + 1);
                const char* Bkt = Bb + ktn * 49152;
#pragma unroll
                for (int r = 0; r < 6; ++r)
                    stage16(Bkt + (size_t)(r * 512 + tid) * 16,
                            sB[ktn & 1] + r * 8192 + w * 1024);
#pragma unroll
                for (int r = 0; r < 2; ++r)
                    stage16c(hin + (size_t)aRow[r] * 1024 + ktn * 256 + aQ[r] * 16,
                             sA[(i + 1) & 1] + r * 8192 + w * 1024);
                asm volatile("s_waitcnt vmcnt(8)" ::: "memory");
            } else if (i == 0) {
                asm volatile("s_waitcnt vmcnt(2)" ::: "memory");
            } else {
                asm volatile("s_waitcnt vmcnt(0)" ::: "memory");
            }
            __syncthreads();
            const char* cA = sA[i & 1];
            const char* cB = sB[kt & 1];
            f16x8 a0[4], a1[4];
#pragma unroll
            for (int kf = 0; kf < 4; ++kf) {
                a0[kf] = *(const f16x8*)(cA + offA[0][kf]);
                a1[kf] = *(const f16x8*)(cA + offA[1][kf]);
            }
#pragma unroll
            for (int g = 0; g < 3; ++g)
#pragma unroll
                for (int kf = 0; kf < 4; ++kf) {
                    f16x8 b = *(const f16x8*)(cB + offB[g][kf]);
                    acc[0][g] = __builtin_amdgcn_mfma_f32_16x16x32_f16(a0[kf], b, acc[0][g], 0, 0, 0);
                    acc[1][g] = __builtin_amdgcn_mfma_f32_16x16x32_f16(a1[kf], b, acc[1][g], 0, 0, 0);
                }
        }

#pragma unroll
        for (int rt = 0; rt < 2; ++rt)
#pragma unroll
            for (int reg = 0; reg < 4; ++reg) {
                int v0 = rt * 12 + reg * 3;
                float gr = (float)((v0 + 0) < 8 ? gv0[(v0 + 0) & 7]
                          : ((v0 + 0) < 16 ? gv1[(v0 + 0) & 7] : gv2[(v0 + 0) & 7]));
                float gz = (float)((v0 + 1) < 8 ? gv0[(v0 + 1) & 7]
                          : ((v0 + 1) < 16 ? gv1[(v0 + 1) & 7] : gv2[(v0 + 1) & 7]));
                float gn = (float)((v0 + 2) < 8 ? gv0[(v0 + 2) & 7]
                          : ((v0 + 2) < 16 ? gv1[(v0 + 2) & 7] : gv2[(v0 + 2) & 7]));
                int row = Mt * 64 + wm * 32 + rt * 16 + qq * 4 + reg;
                float r = 1.f / (1.f + __expf(-(acc[rt][0][reg] + gr + bir + bhr)));
                float z = 1.f / (1.f + __expf(-(acc[rt][1][reg] + gz + biz + bhz)));
                float nn = tanhf(gn + bin + r * (acc[rt][2][reg] + bhn));
                float hv = (1.f - z) * nn + z * hp[rt][reg];
                hp[rt][reg] = hv;
                store_h16(hout + ((size_t)gru * N_ + row) * D_ + j, hv);
            }

        asm volatile("s_waitcnt vmcnt(0)" ::: "memory");   // drain h stores
        __syncthreads();
        if (tid == 0) {
            __hip_atomic_fetch_add(flag, 1u, __ATOMIC_RELAXED, __HIP_MEMORY_SCOPE_AGENT);
            if (it < nsteps - 1) {
                unsigned tgt = 8u * (unsigned)(gstep + 1);
                int guard = 0;
                while (__hip_atomic_load(flag, __ATOMIC_RELAXED, __HIP_MEMORY_SCOPE_AGENT) < tgt) {
                    __builtin_amdgcn_s_sleep(1);
                    if (++guard > (1 << 22)) break;   // bail: fail, don't hang
                }
            }
        }
        if (it < nsteps - 1) {
            const _Float16* gp = giTid0 + (size_t)(it + 1) * giStep;
            gv0 = *(const f16x8*)(gp);
            gv1 = *(const f16x8*)(gp + 8);
            gv2 = *(const f16x8*)(gp + 16);
            __syncthreads();
            int dirn = (gstep + 1) & 1;
            const char* hinN = dirn ? h1 : h0;
#pragma unroll
            for (int s = 0; s < 2; ++s) {
                int kt = dirn ? 3 - s : s;
#pragma unroll
                for (int r = 0; r < 2; ++r)
                    stage16c(hinN + (size_t)aRow[r] * 1024 + kt * 256 + aQ[r] * 16,
                             sA[s & 1] + r * 8192 + w * 1024);
            }
        }
    }
}

// ---------------------------------------------------------------------------
__global__ __launch_bounds__(256) void head_kernel(
    const _Float16* __restrict__ hs2, const _Float16* __restrict__ ht2,
    const float* __restrict__ Wps, const float* __restrict__ bps,
    const float* __restrict__ Wpt, const float* __restrict__ bpt,
    const float* __restrict__ x, float* __restrict__ out) {
    int g = blockIdx.x * 256 + threadIdx.x;
    int n = g >> 4, p = g & 15;
    int b = n >> 5, c = n & 31;
    const _Float16* hs = hs2 + (size_t)n * D_;
    const _Float16* ht = ht2 + (size_t)n * D_;
    const float* ws = Wps + (size_t)p * D_;
    const float* wt = Wpt + (size_t)p * D_;
    float acc = bps[p] + bpt[p];
    for (int k = 0; k < D_; ++k)
        acc += (float)hs[k] * ws[k] + (float)ht[k] * wt[k];
    float last = x[((size_t)b * L_ + (L_ - 1)) * C_ + c];
    out[((size_t)b * SEG_ + p) * C_ + c] = acc + last;
}

// ---------------------------------------------------------------------------
extern "C" void kernel_launch(void* const* d_in, const int* in_sizes, int n_in,
                              void* d_out, int out_size, void* d_ws, size_t ws_size,
                              hipStream_t stream) {
    const float* x     = (const float*)d_in[0];
    const float* W_emb = (const float*)d_in[1];
    const float* b_emb = (const float*)d_in[2];
    const float* Wih_s = (const float*)d_in[3];
    const float* Whh_s = (const float*)d_in[4];
    const float* bih_s = (const float*)d_in[5];
    const float* bhh_s = (const float*)d_in[6];
    const float* Wih_t = (const float*)d_in[7];
    const float* Whh_t = (const float*)d_in[8];
    const float* bih_t = (const float*)d_in[9];
    const float* bhh_t = (const float*)d_in[10];
    const float* pos_s = (const float*)d_in[11];
    const float* ch_s  = (const float*)d_in[12];
    const float* pos_t = (const float*)d_in[13];
    const float* ch_t  = (const float*)d_in[14];
    const float* Wps   = (const float*)d_in[15];
    const float* bps   = (const float*)d_in[16];
    const float* Wpt   = (const float*)d_in[17];
    const float* bpt   = (const float*)d_in[18];
    float* out = (float*)d_out;

    char* p = (char*)d_ws;
    float* xs_seg = (float*)p;          p += (size_t)SX_ * N_ * SEG_ * 4;        // 4 MB
    float* xt_seg = (float*)p;          p += (size_t)SX_ * N_ * SEG_ * 4;        // 4 MB
    _Float16* emb_buf = (_Float16*)p;   p += (size_t)16 * 2 * N_ * D_ * 2;       // 32 MB
    _Float16* gi_buf  = (_Float16*)p;   p += (size_t)16 * 2 * 8 * 16 * 512 * 24 * 2; // 96 MB
    _Float16* gi_pe   = (_Float16*)p;   p += (size_t)2 * 8 * 16 * 512 * 24 * 2;  // 6 MB
    _Float16* pe_buf  = (_Float16*)p;   p += (size_t)2 * N_ * D_ * 2;            // 2 MB
    _Float16* wih_pk  = (_Float16*)p;   p += (size_t)2 * 16 * 1536 * 32 * 2;     // 3 MB
    _Float16* whh_pk5 = (_Float16*)p;   p += (size_t)2 * 8 * 4 * 3072 * 8 * 2;   // 3 MB
    _Float16* hbf0 = (_Float16*)p;      p += (size_t)2 * N_ * D_ * 2;            // 2 MB
    _Float16* hbf1 = (_Float16*)p;      p += (size_t)2 * N_ * D_ * 2;            // 2 MB
    unsigned* flags = (unsigned*)p;     p += 32 * 32 * 4;                        // 4 KB

    hipMemsetAsync(hbf0, 0, (size_t)2 * N_ * D_ * 2, stream);
    hipMemsetAsync(flags, 0, 32 * 32 * 4, stream);

    pack_wih_kernel<<<6144, 256, 0, stream>>>(Wih_s, Wih_t, wih_pk);
    pack_whh5_kernel<<<6144, 256, 0, stream>>>(Whh_s, Whh_t, whh_pk5);
    pack_pe_kernel<<<4096, 256, 0, stream>>>(pos_s, ch_s, pos_t, ch_t, pe_buf);
    prep_kernel<<<B_ * 4, 256, 0, stream>>>(x, xs_seg, xt_seg);

    for (int b = 0; b < 4; ++b) {
        emb_kernel<<<512, 256, 0, stream>>>(xs_seg, xt_seg, W_emb, b_emb, emb_buf, b * 16);
        gi_gemm_kernel<<<dim3(64, 16, 2), 512, 0, stream>>>(
            emb_buf, pe_buf, wih_pk, gi_buf, gi_pe, 0);
        gru_chain_kernel<<<256, 512, 0, stream>>>(
            whh_pk5, gi_buf, bih_s, bhh_s, bih_t, bhh_t,
            hbf0, hbf1, flags, 16, b * 16);
    }
    // decoder: gi from pe, one step (hbf0 -> hbf1)
    gi_gemm_kernel<<<dim3(64, 1, 2), 512, 0, stream>>>(
        emb_buf, pe_buf, wih_pk, gi_buf, gi_pe, 1);
    gru_chain_kernel<<<256, 512, 0, stream>>>(
        whh_pk5, gi_pe, bih_s, bhh_s, bih_t, bhh_t,
        hbf0, hbf1, flags, 1, 64);

    head_kernel<<<N_ * SEG_ / 256, 256, 0, stream>>>(
        hbf1, hbf1 + (size_t)N_ * D_, Wps, bps, Wpt, bpt, x, out);
}